// Round 1
// baseline (365.298 us; speedup 1.0000x reference)
//
#include <hip/hip_runtime.h>
#include <hip/hip_bf16.h>

// Problem constants
#define B_   8
#define NQ_  2048
#define NKV_ 2048
#define DQ_  512
#define DIN_ 512

using f32x4  = __attribute__((ext_vector_type(4))) float;
using bf16x4 = __attribute__((ext_vector_type(4))) __bf16;
using bf16x8 = __attribute__((ext_vector_type(8))) __bf16;

__device__ __forceinline__ f32x4 mfma16(bf16x8 a, bf16x8 b, f32x4 c) {
  return __builtin_amdgcn_mfma_f32_16x16x32_bf16(a, b, c, 0, 0, 0);
}

// ---------------------------------------------------------------------------
// Generic NT GEMM: C[m,n] = sum_k A[m,k]*B[n,k] (+ epilogue), fp32 in/out.
// fp32 operands are split on the fly into bf16 hi/lo; products:
//   AT=2,BT=2 -> hh + hl + lh   (near-fp32 accuracy)
//   AT=1,BT=2 -> hh + hl
// Tile 128x128, BK=64, 4 waves, each wave 64x64 via 4x4 frags of 16x16x32.
// M,N multiples of 128; K multiple of 64.
// EPI: 0 none; 1 +bias[n]; 2 +bias[n] + key[(m & 2047)*512 + n]
// ---------------------------------------------------------------------------
template<int AT, int BT, int EPI>
__global__ __launch_bounds__(256, 2)
void gemm_nt(const float* __restrict__ A, const float* __restrict__ Bm,
             float* __restrict__ C, int M, int N, int K,
             int ldA, int ldB, int ldC,
             long long sA, long long sB, long long sC,
             const float* __restrict__ bias, const float* __restrict__ keyp)
{
  (void)M; (void)N;
  constexpr int PAD = 8;                       // +16B pad -> 2-way (free) LDS conflicts
  __shared__ __bf16 Ah[128][64 + PAD];
  __shared__ __bf16 Al[(AT == 2) ? 128 : 1][64 + PAD];
  __shared__ __bf16 Bh[128][64 + PAD];
  __shared__ __bf16 Bl[(BT == 2) ? 128 : 1][64 + PAD];

  const int tid  = threadIdx.x;
  const int lane = tid & 63;
  const int w    = tid >> 6;      // wave 0..3
  const int wr   = w >> 1;        // wave row (0..1)
  const int wc   = w & 1;         // wave col (0..1)
  const int brow = blockIdx.y * 128;
  const int bcol = blockIdx.x * 128;

  const float* Ag = A  + (size_t)blockIdx.z * sA + (size_t)brow * ldA;
  const float* Bg = Bm + (size_t)blockIdx.z * sB + (size_t)bcol * ldB;
  float*       Cg = C  + (size_t)blockIdx.z * sC;

  f32x4 acc[4][4] = {};

  const int sr = tid >> 4;         // staging row 0..15
  const int sc = (tid & 15) * 4;   // staging col (floats)

  for (int k0 = 0; k0 < K; k0 += 64) {
    __syncthreads();               // LDS safe to overwrite
    // ---- stage A tile [128 x 64] fp32 -> bf16 hi/lo ----
#pragma unroll
    for (int p = 0; p < 8; ++p) {
      const int r = p * 16 + sr;
      const float4 v = *(const float4*)(Ag + (size_t)r * ldA + k0 + sc);
      const float vv[4] = {v.x, v.y, v.z, v.w};
      bf16x4 h, l;
#pragma unroll
      for (int j = 0; j < 4; ++j) {
        const __bf16 hb = (__bf16)vv[j];
        h[j] = hb;
        if (AT == 2) l[j] = (__bf16)(vv[j] - (float)hb);
      }
      *(bf16x4*)&Ah[r][sc] = h;
      if (AT == 2) *(bf16x4*)&Al[r][sc] = l;
    }
    // ---- stage B tile [128 x 64] ----
#pragma unroll
    for (int p = 0; p < 8; ++p) {
      const int r = p * 16 + sr;
      const float4 v = *(const float4*)(Bg + (size_t)r * ldB + k0 + sc);
      const float vv[4] = {v.x, v.y, v.z, v.w};
      bf16x4 h, l;
#pragma unroll
      for (int j = 0; j < 4; ++j) {
        const __bf16 hb = (__bf16)vv[j];
        h[j] = hb;
        if (BT == 2) l[j] = (__bf16)(vv[j] - (float)hb);
      }
      *(bf16x4*)&Bh[r][sc] = h;
      if (BT == 2) *(bf16x4*)&Bl[r][sc] = l;
    }
    __syncthreads();
    // ---- compute: 2 k-chunks of 32 ----
#pragma unroll
    for (int kk = 0; kk < 2; ++kk) {
      const int fr = lane & 15;
      const int fc = kk * 32 + (lane >> 4) * 8;
      bf16x8 ah[4], al[4], bh[4], bl[4];
#pragma unroll
      for (int m = 0; m < 4; ++m) {
        ah[m] = *(const bf16x8*)&Ah[wr * 64 + m * 16 + fr][fc];
        if (AT == 2) al[m] = *(const bf16x8*)&Al[wr * 64 + m * 16 + fr][fc];
      }
#pragma unroll
      for (int n = 0; n < 4; ++n) {
        bh[n] = *(const bf16x8*)&Bh[wc * 64 + n * 16 + fr][fc];
        if (BT == 2) bl[n] = *(const bf16x8*)&Bl[wc * 64 + n * 16 + fr][fc];
      }
#pragma unroll
      for (int m = 0; m < 4; ++m)
#pragma unroll
        for (int n = 0; n < 4; ++n) {
          acc[m][n] = mfma16(ah[m], bh[n], acc[m][n]);
          if (BT == 2) acc[m][n] = mfma16(ah[m], bl[n], acc[m][n]);
          if (AT == 2) acc[m][n] = mfma16(al[m], bh[n], acc[m][n]);
        }
    }
  }

  // ---- epilogue: C/D frag layout col=lane&15, row=(lane>>4)*4+r ----
#pragma unroll
  for (int m = 0; m < 4; ++m)
#pragma unroll
    for (int n = 0; n < 4; ++n)
#pragma unroll
      for (int r = 0; r < 4; ++r) {
        const int row_g = brow + wr * 64 + m * 16 + (lane >> 4) * 4 + r;
        const int col_g = bcol + wc * 64 + n * 16 + (lane & 15);
        float vv = acc[m][n][r];
        if (EPI >= 1) vv += bias[col_g];
        if (EPI == 2) vv += keyp[(size_t)(row_g & (NKV_ - 1)) * DQ_ + col_g];
        Cg[(size_t)row_g * ldC + col_g] = vv;
      }
}

// ---------------------------------------------------------------------------
// x [B, NKV, DIN] -> xT [B, DIN, NKV]  (fp32 tiled transpose)
// ---------------------------------------------------------------------------
__global__ void transpose_x(const float* __restrict__ x, float* __restrict__ xT)
{
  __shared__ float tile[32][33];
  const int b  = blockIdx.z;
  const int j0 = blockIdx.x * 32;   // NKV index
  const int i0 = blockIdx.y * 32;   // DIN index
  const float* xs = x  + (size_t)b * NKV_ * DIN_;
  float*       xd = xT + (size_t)b * DIN_ * NKV_;
  const int tx = threadIdx.x, ty = threadIdx.y;  // 32 x 8
#pragma unroll
  for (int p = 0; p < 32; p += 8)
    tile[ty + p][tx] = xs[(size_t)(j0 + ty + p) * DIN_ + i0 + tx];
  __syncthreads();
#pragma unroll
  for (int p = 0; p < 32; p += 8)
    xd[(size_t)(i0 + ty + p) * NKV_ + j0 + tx] = tile[tx][ty + p];
}

// ---------------------------------------------------------------------------
// In-place row softmax over attn [rows x 2048], one wave per row.
// ---------------------------------------------------------------------------
__global__ void softmax_rows(float* __restrict__ attn)
{
  const int lane = threadIdx.x & 63;
  const int wv   = threadIdx.x >> 6;
  const size_t row = (size_t)blockIdx.x * 4 + wv;
  float* p = attn + row * NKV_;

  float4 v[8];
  float mx = -1e30f;
#pragma unroll
  for (int i = 0; i < 8; ++i) {
    v[i] = *(const float4*)&p[i * 256 + lane * 4];
    mx = fmaxf(mx, fmaxf(fmaxf(v[i].x, v[i].y), fmaxf(v[i].z, v[i].w)));
  }
#pragma unroll
  for (int off = 32; off; off >>= 1) mx = fmaxf(mx, __shfl_xor(mx, off, 64));

  float sum = 0.f;
#pragma unroll
  for (int i = 0; i < 8; ++i) {
    v[i].x = expf(v[i].x - mx);
    v[i].y = expf(v[i].y - mx);
    v[i].z = expf(v[i].z - mx);
    v[i].w = expf(v[i].w - mx);
    sum += v[i].x + v[i].y + v[i].z + v[i].w;
  }
#pragma unroll
  for (int off = 32; off; off >>= 1) sum += __shfl_xor(sum, off, 64);

  const float inv = 1.0f / sum;
#pragma unroll
  for (int i = 0; i < 8; ++i) {
    v[i].x *= inv; v[i].y *= inv; v[i].z *= inv; v[i].w *= inv;
    *(float4*)&p[i * 256 + lane * 4] = v[i];
  }
}

// ---------------------------------------------------------------------------
extern "C" void kernel_launch(void* const* d_in, const int* in_sizes, int n_in,
                              void* d_out, int out_size, void* d_ws, size_t ws_size,
                              hipStream_t stream)
{
  (void)in_sizes; (void)n_in; (void)out_size; (void)ws_size;
  const float* query  = (const float*)d_in[0];  // [8, 2048, 512]
  const float* key    = (const float*)d_in[1];  // [2048, 512]
  const float* x      = (const float*)d_in[2];  // [8, 2048, 512]
  const float* W_proj = (const float*)d_in[3];  // [512, 512]
  const float* b_proj = (const float*)d_in[4];  // [512]
  const float* W_px   = (const float*)d_in[5];  // [512, 512]
  const float* b_px   = (const float*)d_in[6];  // [512]

  float* out  = (float*)d_out;                          // [8, 2048, 512]
  float* attn = out + (size_t)B_ * NQ_ * DIN_;          // [8, 2048, 2048]

  float* qp   = (float*)d_ws;                           // [16384, 512]
  float* kmat = qp   + (size_t)B_ * NQ_  * DQ_;         // [16384, 512]
  float* xT   = kmat + (size_t)B_ * NKV_ * DQ_;         // [8, 512, 2048]

  const long long PQ = (long long)NQ_  * DQ_;    // 2048*512
  const long long PS = (long long)NQ_  * NKV_;   // 2048*2048
  const long long PX = (long long)DIN_ * NKV_;   // 512*2048

  // x^T for the PV GEMM B-operand
  transpose_x<<<dim3(NKV_ / 32, DIN_ / 32, B_), dim3(32, 8), 0, stream>>>(x, xT);

  // q_proj = query @ W_proj^T + b_proj
  gemm_nt<2, 2, 1><<<dim3(DQ_ / 128, (B_ * NQ_) / 128, 1), 256, 0, stream>>>(
      query, W_proj, qp, B_ * NQ_, DQ_, DQ_, DQ_, DQ_, DQ_, 0, 0, 0, b_proj, nullptr);

  // k = x @ W_px^T + b_px + key
  gemm_nt<2, 2, 2><<<dim3(DQ_ / 128, (B_ * NKV_) / 128, 1), 256, 0, stream>>>(
      x, W_px, kmat, B_ * NKV_, DQ_, DIN_, DIN_, DIN_, DQ_, 0, 0, 0, b_px, key);

  // score[b] = q_proj[b] @ k[b]^T   -> written into attn region of d_out
  gemm_nt<2, 2, 0><<<dim3(NKV_ / 128, NQ_ / 128, B_), 256, 0, stream>>>(
      qp, kmat, attn, NQ_, NKV_, DQ_, DQ_, DQ_, NKV_, PQ, PQ, PS, nullptr, nullptr);

  // softmax rows in place
  softmax_rows<<<(B_ * NQ_) / 4, 256, 0, stream>>>(attn);

  // out[b] = attn[b] @ x[b]  (= attn @ xT^T, NT form)
  gemm_nt<1, 2, 0><<<dim3(DIN_ / 128, NQ_ / 128, B_), 256, 0, stream>>>(
      attn, xT, out, NQ_, DIN_, NKV_, NKV_, NKV_, DIN_, PS, PX, PQ, nullptr, nullptr);
}

// Round 2
// 348.403 us; speedup vs baseline: 1.0485x; 1.0485x over previous
//
#include <hip/hip_runtime.h>
#include <hip/hip_bf16.h>

// Problem constants
#define B_   8
#define NQ_  2048
#define NKV_ 2048
#define DQ_  512
#define DIN_ 512

using f32x4  = __attribute__((ext_vector_type(4))) float;
using bf16x4 = __attribute__((ext_vector_type(4))) __bf16;
using bf16x8 = __attribute__((ext_vector_type(8))) __bf16;

__device__ __forceinline__ f32x4 mfma16(bf16x8 a, bf16x8 b, f32x4 c) {
  return __builtin_amdgcn_mfma_f32_16x16x32_bf16(a, b, c, 0, 0, 0);
}

// async global->LDS, 16B per lane. LDS dest must be wave-uniform base (+lane*16 in HW).
__device__ __forceinline__ void gload_lds16(const __bf16* g, __bf16* l) {
  __builtin_amdgcn_global_load_lds(
      (const __attribute__((address_space(1))) void*)g,
      (__attribute__((address_space(3))) void*)l, 16, 0, 0);
}

// ---------------------------------------------------------------------------
// Projection GEMM: C[m,n] = sum_k A[m,k]*B[n,k] + bias[n] (+ key), fp32 in,
// SPLIT bf16 hi/lo out. 3-product split accumulation (hh+hl+lh).
// M=16384, N=512, K=512. Tile 128x128, BK=64, 4 waves.
// EPI: 1 +bias[n]; 2 +bias[n] + key[(m&2047)*512+n]
// ---------------------------------------------------------------------------
template<int EPI>
__global__ __launch_bounds__(256, 2)
void proj_gemm(const float* __restrict__ A, const float* __restrict__ Bm,
               __bf16* __restrict__ Ch, __bf16* __restrict__ Cl,
               const float* __restrict__ bias, const float* __restrict__ keyp)
{
  constexpr int PAD = 8;
  __shared__ __bf16 Ah[128][64 + PAD];
  __shared__ __bf16 Al[128][64 + PAD];
  __shared__ __bf16 Bh[128][64 + PAD];
  __shared__ __bf16 Bl[128][64 + PAD];

  const int tid  = threadIdx.x;
  const int lane = tid & 63;
  const int w    = tid >> 6;
  const int wr   = w >> 1;
  const int wc   = w & 1;
  const int brow = blockIdx.y * 128;
  const int bcol = blockIdx.x * 128;

  const float* Ag = A  + (size_t)brow * DQ_;
  const float* Bg = Bm + (size_t)bcol * DQ_;

  f32x4 acc[4][4] = {};

  const int sr = tid >> 4;
  const int sc = (tid & 15) * 4;

  for (int k0 = 0; k0 < DQ_; k0 += 64) {
    __syncthreads();
#pragma unroll
    for (int p = 0; p < 8; ++p) {
      const int r = p * 16 + sr;
      const float4 v = *(const float4*)(Ag + (size_t)r * DQ_ + k0 + sc);
      const float vv[4] = {v.x, v.y, v.z, v.w};
      bf16x4 h, l;
#pragma unroll
      for (int j = 0; j < 4; ++j) {
        const __bf16 hb = (__bf16)vv[j];
        h[j] = hb;
        l[j] = (__bf16)(vv[j] - (float)hb);
      }
      *(bf16x4*)&Ah[r][sc] = h;
      *(bf16x4*)&Al[r][sc] = l;
    }
#pragma unroll
    for (int p = 0; p < 8; ++p) {
      const int r = p * 16 + sr;
      const float4 v = *(const float4*)(Bg + (size_t)r * DQ_ + k0 + sc);
      const float vv[4] = {v.x, v.y, v.z, v.w};
      bf16x4 h, l;
#pragma unroll
      for (int j = 0; j < 4; ++j) {
        const __bf16 hb = (__bf16)vv[j];
        h[j] = hb;
        l[j] = (__bf16)(vv[j] - (float)hb);
      }
      *(bf16x4*)&Bh[r][sc] = h;
      *(bf16x4*)&Bl[r][sc] = l;
    }
    __syncthreads();
#pragma unroll
    for (int kk = 0; kk < 2; ++kk) {
      const int fr = lane & 15;
      const int fc = kk * 32 + (lane >> 4) * 8;
      bf16x8 ah[4], al[4], bh[4], bl[4];
#pragma unroll
      for (int m = 0; m < 4; ++m) {
        ah[m] = *(const bf16x8*)&Ah[wr * 64 + m * 16 + fr][fc];
        al[m] = *(const bf16x8*)&Al[wr * 64 + m * 16 + fr][fc];
      }
#pragma unroll
      for (int n = 0; n < 4; ++n) {
        bh[n] = *(const bf16x8*)&Bh[wc * 64 + n * 16 + fr][fc];
        bl[n] = *(const bf16x8*)&Bl[wc * 64 + n * 16 + fr][fc];
      }
#pragma unroll
      for (int m = 0; m < 4; ++m)
#pragma unroll
        for (int n = 0; n < 4; ++n) {
          acc[m][n] = mfma16(ah[m], bh[n], acc[m][n]);
          acc[m][n] = mfma16(ah[m], bl[n], acc[m][n]);
          acc[m][n] = mfma16(al[m], bh[n], acc[m][n]);
        }
    }
  }

#pragma unroll
  for (int m = 0; m < 4; ++m)
#pragma unroll
    for (int n = 0; n < 4; ++n)
#pragma unroll
      for (int r = 0; r < 4; ++r) {
        const int row_g = brow + wr * 64 + m * 16 + (lane >> 4) * 4 + r;
        const int col_g = bcol + wc * 64 + n * 16 + (lane & 15);
        float vv = acc[m][n][r] + bias[col_g];
        if (EPI == 2) vv += keyp[(size_t)(row_g & (NKV_ - 1)) * DQ_ + col_g];
        const __bf16 h = (__bf16)vv;
        Ch[(size_t)row_g * DQ_ + col_g] = h;
        Cl[(size_t)row_g * DQ_ + col_g] = (__bf16)(vv - (float)h);
      }
}

// ---------------------------------------------------------------------------
// Score GEMM: attn_raw[b,q,j] = qp[b,q,:] . km[b,j,:] with 3-product split.
// Operands pre-split bf16 (h/l arrays). Pure global_load_lds staging with
// XOR slot swizzle (slot ^= row&7 within 128B rows), BK=32 per step.
// LDS tile [128 rows][64 cols]: cols 0..31 = hi K-chunk, 32..63 = lo.
// ---------------------------------------------------------------------------
__global__ __launch_bounds__(256, 2)
void score_gemm(const __bf16* __restrict__ qph, const __bf16* __restrict__ qpl,
                const __bf16* __restrict__ kmh, const __bf16* __restrict__ kml,
                float* __restrict__ attn)
{
  __shared__ __bf16 At[128 * 64];
  __shared__ __bf16 Bt[128 * 64];

  const int t    = threadIdx.x;
  const int lane = t & 63;
  const int w    = t >> 6;
  const int wr   = w >> 1;
  const int wc   = w & 1;
  const int b    = blockIdx.z;
  const int brow = blockIdx.y * 128;
  const int bcol = blockIdx.x * 128;

  // staging constants: row within tile = i*32 + t/8, lds slot = t%8
  const int srow = t >> 3;                 // 0..31
  const int sslot = t & 7;
  const int sig  = sslot ^ (srow & 7);     // logical slot (const across issues/steps)
  const size_t arow0 = (size_t)b * NQ_  + brow;
  const size_t brow0 = (size_t)b * NKV_ + bcol;
  const __bf16* aG = (sig < 4 ? qph : qpl) + (arow0 + srow) * DQ_ + (sig & 3) * 8;
  const __bf16* bG = (sig < 4 ? kmh : kml) + (brow0 + srow) * DQ_ + (sig & 3) * 8;
  __bf16* aL = At + w * 512;               // wave-uniform; +i*2048 per issue
  __bf16* bL = Bt + w * 512;

  f32x4 acc[4][4] = {};
  const int fr = lane & 15;
  const int q  = lane >> 4;

  for (int ks = 0; ks < 16; ++ks) {        // K=512, 32 per step
    __syncthreads();
#pragma unroll
    for (int i = 0; i < 4; ++i) {
      gload_lds16(aG + (size_t)i * 32 * DQ_, aL + i * 2048);
      gload_lds16(bG + (size_t)i * 32 * DQ_, bL + i * 2048);
    }
    aG += 32; bG += 32;
    __syncthreads();

    bf16x8 ah[4], al[4], bh[4], bl[4];
#pragma unroll
    for (int m = 0; m < 4; ++m) {
      const int rt = wr * 64 + m * 16 + fr;
      ah[m] = *(const bf16x8*)&At[rt * 64 + ((q       ^ (rt & 7)) * 8)];
      al[m] = *(const bf16x8*)&At[rt * 64 + (((4 + q) ^ (rt & 7)) * 8)];
    }
#pragma unroll
    for (int n = 0; n < 4; ++n) {
      const int rt = wc * 64 + n * 16 + fr;
      bh[n] = *(const bf16x8*)&Bt[rt * 64 + ((q       ^ (rt & 7)) * 8)];
      bl[n] = *(const bf16x8*)&Bt[rt * 64 + (((4 + q) ^ (rt & 7)) * 8)];
    }
#pragma unroll
    for (int m = 0; m < 4; ++m)
#pragma unroll
      for (int n = 0; n < 4; ++n) {
        acc[m][n] = mfma16(ah[m], bh[n], acc[m][n]);
        acc[m][n] = mfma16(ah[m], bl[n], acc[m][n]);
        acc[m][n] = mfma16(al[m], bh[n], acc[m][n]);
      }
  }

  float* Cg = attn + (size_t)b * NQ_ * NKV_;
#pragma unroll
  for (int m = 0; m < 4; ++m)
#pragma unroll
    for (int n = 0; n < 4; ++n)
#pragma unroll
      for (int r = 0; r < 4; ++r) {
        const int row_g = brow + wr * 64 + m * 16 + q * 4 + r;
        const int col_g = bcol + wc * 64 + n * 16 + fr;
        Cg[(size_t)row_g * NKV_ + col_g] = acc[m][n][r];
      }
}

// ---------------------------------------------------------------------------
// PV GEMM: out[b,q,n] = sum_j attn[b,q,j] * xT[b,n,j]. Single bf16 product.
// A (attn fp32) reg-staged + converted to bf16 in padded LDS; B (xT bf16)
// global_load_lds with XOR swizzle. BK=64.
// ---------------------------------------------------------------------------
__global__ __launch_bounds__(256, 2)
void pv_gemm(const float* __restrict__ attn, const __bf16* __restrict__ xT,
             float* __restrict__ out)
{
  constexpr int PAD = 8;
  __shared__ __bf16 At[128][64 + PAD];
  __shared__ __bf16 Bt[128 * 64];

  const int t    = threadIdx.x;
  const int lane = t & 63;
  const int w    = t >> 6;
  const int wr   = w >> 1;
  const int wc   = w & 1;
  const int b    = blockIdx.z;
  const int brow = blockIdx.y * 128;   // q rows
  const int bcol = blockIdx.x * 128;   // din cols

  const float* Ag = attn + (size_t)b * NQ_ * NKV_ + (size_t)brow * NKV_;

  const int srB = t >> 3, sB = t & 7;
  const int sigB = sB ^ (srB & 7);
  const __bf16* bG = xT + (size_t)b * DIN_ * NKV_ + (size_t)(bcol + srB) * NKV_ + sigB * 8;
  __bf16* bL = Bt + w * 512;

  const int srA = t >> 4, scA = (t & 15) * 4;

  f32x4 acc[4][4] = {};
  const int fr = lane & 15;
  const int q  = lane >> 4;

  for (int ks = 0; ks < NKV_ / 64; ++ks) {
    const int k0 = ks * 64;
    __syncthreads();
#pragma unroll
    for (int i = 0; i < 4; ++i)
      gload_lds16(bG + (size_t)i * 32 * NKV_, bL + i * 2048);
    bG += 64;
#pragma unroll
    for (int p = 0; p < 8; ++p) {
      const int r = p * 16 + srA;
      const float4 v = *(const float4*)(Ag + (size_t)r * NKV_ + k0 + scA);
      bf16x4 hv;
      hv[0] = (__bf16)v.x; hv[1] = (__bf16)v.y; hv[2] = (__bf16)v.z; hv[3] = (__bf16)v.w;
      *(bf16x4*)&At[r][scA] = hv;
    }
    __syncthreads();
#pragma unroll
    for (int kk = 0; kk < 2; ++kk) {
      bf16x8 ah[4], bh[4];
#pragma unroll
      for (int m = 0; m < 4; ++m)
        ah[m] = *(const bf16x8*)&At[wr * 64 + m * 16 + fr][kk * 32 + q * 8];
#pragma unroll
      for (int n = 0; n < 4; ++n) {
        const int rt = wc * 64 + n * 16 + fr;
        bh[n] = *(const bf16x8*)&Bt[rt * 64 + (((kk * 4 + q) ^ (rt & 7)) * 8)];
      }
#pragma unroll
      for (int m = 0; m < 4; ++m)
#pragma unroll
        for (int n = 0; n < 4; ++n)
          acc[m][n] = mfma16(ah[m], bh[n], acc[m][n]);
    }
  }

  float* Cg = out + (size_t)b * NQ_ * DIN_;
#pragma unroll
  for (int m = 0; m < 4; ++m)
#pragma unroll
    for (int n = 0; n < 4; ++n)
#pragma unroll
      for (int r = 0; r < 4; ++r) {
        const int row_g = brow + wr * 64 + m * 16 + q * 4 + r;
        const int col_g = bcol + wc * 64 + n * 16 + fr;
        Cg[(size_t)row_g * DIN_ + col_g] = acc[m][n][r];
      }
}

// ---------------------------------------------------------------------------
// x [B, NKV, DIN] fp32 -> xT [B, DIN, NKV] bf16
// ---------------------------------------------------------------------------
__global__ void transpose_x(const float* __restrict__ x, __bf16* __restrict__ xT)
{
  __shared__ float tile[32][33];
  const int b  = blockIdx.z;
  const int j0 = blockIdx.x * 32;   // NKV index
  const int i0 = blockIdx.y * 32;   // DIN index
  const float* xs = x  + (size_t)b * NKV_ * DIN_;
  __bf16*      xd = xT + (size_t)b * DIN_ * NKV_;
  const int tx = threadIdx.x, ty = threadIdx.y;  // 32 x 8
#pragma unroll
  for (int p = 0; p < 32; p += 8)
    tile[ty + p][tx] = xs[(size_t)(j0 + ty + p) * DIN_ + i0 + tx];
  __syncthreads();
#pragma unroll
  for (int p = 0; p < 32; p += 8)
    xd[(size_t)(i0 + ty + p) * NKV_ + j0 + tx] = (__bf16)tile[tx][ty + p];
}

// ---------------------------------------------------------------------------
// In-place row softmax over attn [rows x 2048], one wave per row.
// ---------------------------------------------------------------------------
__global__ void softmax_rows(float* __restrict__ attn)
{
  const int lane = threadIdx.x & 63;
  const int wv   = threadIdx.x >> 6;
  const size_t row = (size_t)blockIdx.x * 4 + wv;
  float* p = attn + row * NKV_;

  float4 v[8];
  float mx = -1e30f;
#pragma unroll
  for (int i = 0; i < 8; ++i) {
    v[i] = *(const float4*)&p[i * 256 + lane * 4];
    mx = fmaxf(mx, fmaxf(fmaxf(v[i].x, v[i].y), fmaxf(v[i].z, v[i].w)));
  }
#pragma unroll
  for (int off = 32; off; off >>= 1) mx = fmaxf(mx, __shfl_xor(mx, off, 64));

  float sum = 0.f;
#pragma unroll
  for (int i = 0; i < 8; ++i) {
    v[i].x = expf(v[i].x - mx);
    v[i].y = expf(v[i].y - mx);
    v[i].z = expf(v[i].z - mx);
    v[i].w = expf(v[i].w - mx);
    sum += v[i].x + v[i].y + v[i].z + v[i].w;
  }
#pragma unroll
  for (int off = 32; off; off >>= 1) sum += __shfl_xor(sum, off, 64);

  const float inv = 1.0f / sum;
#pragma unroll
  for (int i = 0; i < 8; ++i) {
    v[i].x *= inv; v[i].y *= inv; v[i].z *= inv; v[i].w *= inv;
    *(float4*)&p[i * 256 + lane * 4] = v[i];
  }
}

// ---------------------------------------------------------------------------
extern "C" void kernel_launch(void* const* d_in, const int* in_sizes, int n_in,
                              void* d_out, int out_size, void* d_ws, size_t ws_size,
                              hipStream_t stream)
{
  (void)in_sizes; (void)n_in; (void)out_size; (void)ws_size;
  const float* query  = (const float*)d_in[0];  // [8, 2048, 512]
  const float* key    = (const float*)d_in[1];  // [2048, 512]
  const float* x      = (const float*)d_in[2];  // [8, 2048, 512]
  const float* W_proj = (const float*)d_in[3];  // [512, 512]
  const float* b_proj = (const float*)d_in[4];  // [512]
  const float* W_px   = (const float*)d_in[5];  // [512, 512]
  const float* b_px   = (const float*)d_in[6];  // [512]

  float* out  = (float*)d_out;                          // [8, 2048, 512]
  float* attn = out + (size_t)B_ * NQ_ * DIN_;          // [8, 2048, 2048]

  const size_t PQE = (size_t)B_ * NQ_ * DQ_;            // 8.39M elements
  __bf16* qph = (__bf16*)d_ws;
  __bf16* qpl = qph + PQE;
  __bf16* kmh = qpl + PQE;
  __bf16* kml = kmh + PQE;
  __bf16* xT  = kml + PQE;                              // [8, 512, 2048] bf16

  // x^T (bf16) for the PV GEMM B-operand
  transpose_x<<<dim3(NKV_ / 32, DIN_ / 32, B_), dim3(32, 8), 0, stream>>>(x, xT);

  // q_proj = query @ W_proj^T + b_proj  -> split bf16
  proj_gemm<1><<<dim3(DQ_ / 128, (B_ * NQ_) / 128, 1), 256, 0, stream>>>(
      query, W_proj, qph, qpl, b_proj, nullptr);

  // k = x @ W_px^T + b_px + key        -> split bf16
  proj_gemm<2><<<dim3(DQ_ / 128, (B_ * NKV_) / 128, 1), 256, 0, stream>>>(
      x, W_px, kmh, kml, b_px, key);

  // raw scores into attn region of d_out
  score_gemm<<<dim3(NKV_ / 128, NQ_ / 128, B_), 256, 0, stream>>>(
      qph, qpl, kmh, kml, attn);

  // softmax rows in place
  softmax_rows<<<(B_ * NQ_) / 4, 256, 0, stream>>>(attn);

  // out[b] = attn[b] @ x[b]
  pv_gemm<<<dim3(DIN_ / 128, NQ_ / 128, B_), 256, 0, stream>>>(attn, xT, out);
}

// Round 3
// 302.540 us; speedup vs baseline: 1.2074x; 1.1516x over previous
//
#include <hip/hip_runtime.h>
#include <hip/hip_bf16.h>

// Problem constants
#define B_   8
#define NQ_  2048
#define NKV_ 2048
#define DQ_  512
#define DIN_ 512

using f32x4  = __attribute__((ext_vector_type(4))) float;
using bf16x4 = __attribute__((ext_vector_type(4))) __bf16;
using bf16x8 = __attribute__((ext_vector_type(8))) __bf16;

__device__ __forceinline__ f32x4 mfma16(bf16x8 a, bf16x8 b, f32x4 c) {
  return __builtin_amdgcn_mfma_f32_16x16x32_bf16(a, b, c, 0, 0, 0);
}

// async global->LDS, 16B per lane. LDS dest is wave-uniform base (+lane*16 in HW).
__device__ __forceinline__ void gload_lds16(const __bf16* g, __bf16* l) {
  __builtin_amdgcn_global_load_lds(
      (const __attribute__((address_space(1))) void*)g,
      (__attribute__((address_space(3))) void*)l, 16, 0, 0);
}

// bijective XCD-aware remap (nwg % 8 == 0)
__device__ __forceinline__ int xcd_swz(int bid, int nwg) {
  const int c = nwg >> 3;
  return (bid & 7) * c + (bid >> 3);
}

// ---------------------------------------------------------------------------
// Projection GEMM: C[m,n] = sum_k A[m,k]*B[n,k] + bias[n] (+ key), fp32 in,
// SPLIT bf16 hi/lo out. 3-product split accumulation (hh+hl+lh).
// ---------------------------------------------------------------------------
template<int EPI>
__global__ __launch_bounds__(256, 2)
void proj_gemm(const float* __restrict__ A, const float* __restrict__ Bm,
               __bf16* __restrict__ Ch, __bf16* __restrict__ Cl,
               const float* __restrict__ bias, const float* __restrict__ keyp)
{
  constexpr int PAD = 8;
  __shared__ __bf16 Ah[128][64 + PAD];
  __shared__ __bf16 Al[128][64 + PAD];
  __shared__ __bf16 Bh[128][64 + PAD];
  __shared__ __bf16 Bl[128][64 + PAD];

  const int tid  = threadIdx.x;
  const int lane = tid & 63;
  const int w    = tid >> 6;
  const int wr   = w >> 1;
  const int wc   = w & 1;
  const int brow = blockIdx.y * 128;
  const int bcol = blockIdx.x * 128;

  const float* Ag = A  + (size_t)brow * DQ_;
  const float* Bg = Bm + (size_t)bcol * DQ_;

  f32x4 acc[4][4] = {};

  const int sr = tid >> 4;
  const int sc = (tid & 15) * 4;

  for (int k0 = 0; k0 < DQ_; k0 += 64) {
    __syncthreads();
#pragma unroll
    for (int p = 0; p < 8; ++p) {
      const int r = p * 16 + sr;
      const float4 v = *(const float4*)(Ag + (size_t)r * DQ_ + k0 + sc);
      const float vv[4] = {v.x, v.y, v.z, v.w};
      bf16x4 h, l;
#pragma unroll
      for (int j = 0; j < 4; ++j) {
        const __bf16 hb = (__bf16)vv[j];
        h[j] = hb;
        l[j] = (__bf16)(vv[j] - (float)hb);
      }
      *(bf16x4*)&Ah[r][sc] = h;
      *(bf16x4*)&Al[r][sc] = l;
    }
#pragma unroll
    for (int p = 0; p < 8; ++p) {
      const int r = p * 16 + sr;
      const float4 v = *(const float4*)(Bg + (size_t)r * DQ_ + k0 + sc);
      const float vv[4] = {v.x, v.y, v.z, v.w};
      bf16x4 h, l;
#pragma unroll
      for (int j = 0; j < 4; ++j) {
        const __bf16 hb = (__bf16)vv[j];
        h[j] = hb;
        l[j] = (__bf16)(vv[j] - (float)hb);
      }
      *(bf16x4*)&Bh[r][sc] = h;
      *(bf16x4*)&Bl[r][sc] = l;
    }
    __syncthreads();
#pragma unroll
    for (int kk = 0; kk < 2; ++kk) {
      const int fr = lane & 15;
      const int fc = kk * 32 + (lane >> 4) * 8;
      bf16x8 ah[4], al[4], bh[4], bl[4];
#pragma unroll
      for (int m = 0; m < 4; ++m) {
        ah[m] = *(const bf16x8*)&Ah[wr * 64 + m * 16 + fr][fc];
        al[m] = *(const bf16x8*)&Al[wr * 64 + m * 16 + fr][fc];
      }
#pragma unroll
      for (int n = 0; n < 4; ++n) {
        bh[n] = *(const bf16x8*)&Bh[wc * 64 + n * 16 + fr][fc];
        bl[n] = *(const bf16x8*)&Bl[wc * 64 + n * 16 + fr][fc];
      }
#pragma unroll
      for (int m = 0; m < 4; ++m)
#pragma unroll
        for (int n = 0; n < 4; ++n) {
          acc[m][n] = mfma16(ah[m], bh[n], acc[m][n]);
          acc[m][n] = mfma16(ah[m], bl[n], acc[m][n]);
          acc[m][n] = mfma16(al[m], bh[n], acc[m][n]);
        }
    }
  }

#pragma unroll
  for (int m = 0; m < 4; ++m)
#pragma unroll
    for (int n = 0; n < 4; ++n)
#pragma unroll
      for (int r = 0; r < 4; ++r) {
        const int row_g = brow + wr * 64 + m * 16 + (lane >> 4) * 4 + r;
        const int col_g = bcol + wc * 64 + n * 16 + (lane & 15);
        float vv = acc[m][n][r] + bias[col_g];
        if (EPI == 2) vv += keyp[(size_t)(row_g & (NKV_ - 1)) * DQ_ + col_g];
        const __bf16 h = (__bf16)vv;
        Ch[(size_t)row_g * DQ_ + col_g] = h;
        Cl[(size_t)row_g * DQ_ + col_g] = (__bf16)(vv - (float)h);
      }
}

// ---------------------------------------------------------------------------
// Score GEMM: attn_raw[b,q,j] = qp[b,q,:] . km[b,j,:], 3-product split.
// Pure global_load_lds staging, XOR slot swizzle, BK=32/step (hi+lo).
// 1D grid with XCD-aware remap; decompose swz -> (bx, by, bz).
// ---------------------------------------------------------------------------
__global__ __launch_bounds__(256, 2)
void score_gemm(const __bf16* __restrict__ qph, const __bf16* __restrict__ qpl,
                const __bf16* __restrict__ kmh, const __bf16* __restrict__ kml,
                float* __restrict__ attn)
{
  __shared__ __bf16 At[128 * 64];
  __shared__ __bf16 Bt[128 * 64];

  const int swz  = xcd_swz(blockIdx.x, gridDim.x);
  const int bx   = swz & 15;          // NKV block
  const int by   = (swz >> 4) & 15;   // NQ block
  const int b    = swz >> 8;          // batch

  const int t    = threadIdx.x;
  const int lane = t & 63;
  const int w    = t >> 6;
  const int wr   = w >> 1;
  const int wc   = w & 1;
  const int brow = by * 128;
  const int bcol = bx * 128;

  const int srow  = t >> 3;
  const int sslot = t & 7;
  const int sig   = sslot ^ (srow & 7);
  const size_t arow0 = (size_t)b * NQ_  + brow;
  const size_t brow0 = (size_t)b * NKV_ + bcol;
  const __bf16* aG = (sig < 4 ? qph : qpl) + (arow0 + srow) * DQ_ + (sig & 3) * 8;
  const __bf16* bG = (sig < 4 ? kmh : kml) + (brow0 + srow) * DQ_ + (sig & 3) * 8;
  __bf16* aL = At + w * 512;
  __bf16* bL = Bt + w * 512;

  f32x4 acc[4][4] = {};
  const int fr = lane & 15;
  const int q  = lane >> 4;

  for (int ks = 0; ks < 16; ++ks) {
    __syncthreads();
#pragma unroll
    for (int i = 0; i < 4; ++i) {
      gload_lds16(aG + (size_t)i * 32 * DQ_, aL + i * 2048);
      gload_lds16(bG + (size_t)i * 32 * DQ_, bL + i * 2048);
    }
    aG += 32; bG += 32;
    __syncthreads();

    bf16x8 ah[4], al[4], bh[4], bl[4];
#pragma unroll
    for (int m = 0; m < 4; ++m) {
      const int rt = wr * 64 + m * 16 + fr;
      ah[m] = *(const bf16x8*)&At[rt * 64 + ((q       ^ (rt & 7)) * 8)];
      al[m] = *(const bf16x8*)&At[rt * 64 + (((4 + q) ^ (rt & 7)) * 8)];
    }
#pragma unroll
    for (int n = 0; n < 4; ++n) {
      const int rt = wc * 64 + n * 16 + fr;
      bh[n] = *(const bf16x8*)&Bt[rt * 64 + ((q       ^ (rt & 7)) * 8)];
      bl[n] = *(const bf16x8*)&Bt[rt * 64 + (((4 + q) ^ (rt & 7)) * 8)];
    }
#pragma unroll
    for (int m = 0; m < 4; ++m)
#pragma unroll
      for (int n = 0; n < 4; ++n) {
        acc[m][n] = mfma16(ah[m], bh[n], acc[m][n]);
        acc[m][n] = mfma16(ah[m], bl[n], acc[m][n]);
        acc[m][n] = mfma16(al[m], bh[n], acc[m][n]);
      }
  }

  float* Cg = attn + (size_t)b * NQ_ * NKV_;
#pragma unroll
  for (int m = 0; m < 4; ++m)
#pragma unroll
    for (int n = 0; n < 4; ++n)
#pragma unroll
      for (int r = 0; r < 4; ++r) {
        const int row_g = brow + wr * 64 + m * 16 + q * 4 + r;
        const int col_g = bcol + wc * 64 + n * 16 + fr;
        Cg[(size_t)row_g * NKV_ + col_g] = acc[m][n][r];
      }
}

// ---------------------------------------------------------------------------
// PV GEMM: out[b,q,n] = sum_j attnb[b,q,j] * xT[b,n,j]. Both operands bf16,
// staged via global_load_lds with XOR swizzle. BK=64, 32 MFMA/step.
// ---------------------------------------------------------------------------
__global__ __launch_bounds__(256, 2)
void pv_gemm(const __bf16* __restrict__ attnb, const __bf16* __restrict__ xT,
             float* __restrict__ out)
{
  __shared__ __bf16 At[128 * 64];
  __shared__ __bf16 Bt[128 * 64];

  const int swz  = xcd_swz(blockIdx.x, gridDim.x);
  const int bx   = swz & 3;           // DIN block
  const int by   = (swz >> 2) & 15;   // NQ block
  const int b    = swz >> 6;          // batch

  const int t    = threadIdx.x;
  const int lane = t & 63;
  const int w    = t >> 6;
  const int wr   = w >> 1;
  const int wc   = w & 1;
  const int brow = by * 128;   // q rows
  const int bcol = bx * 128;   // din cols

  const int srow  = t >> 3;
  const int sslot = t & 7;
  const int sig   = sslot ^ (srow & 7);
  const __bf16* aG = attnb + ((size_t)b * NQ_ + brow + srow) * NKV_ + sig * 8;
  const __bf16* bG = xT + (size_t)b * DIN_ * NKV_ + (size_t)(bcol + srow) * NKV_ + sig * 8;
  __bf16* aL = At + w * 512;
  __bf16* bL = Bt + w * 512;

  f32x4 acc[4][4] = {};
  const int fr = lane & 15;
  const int q  = lane >> 4;

  for (int ks = 0; ks < NKV_ / 64; ++ks) {
    __syncthreads();
#pragma unroll
    for (int i = 0; i < 4; ++i) {
      gload_lds16(aG + (size_t)i * 32 * NKV_, aL + i * 2048);
      gload_lds16(bG + (size_t)i * 32 * NKV_, bL + i * 2048);
    }
    aG += 64; bG += 64;
    __syncthreads();

#pragma unroll
    for (int kk = 0; kk < 2; ++kk) {
      bf16x8 ah[4], bh[4];
#pragma unroll
      for (int m = 0; m < 4; ++m) {
        const int rt = wr * 64 + m * 16 + fr;
        ah[m] = *(const bf16x8*)&At[rt * 64 + (((kk * 4 + q) ^ (rt & 7)) * 8)];
      }
#pragma unroll
      for (int n = 0; n < 4; ++n) {
        const int rt = wc * 64 + n * 16 + fr;
        bh[n] = *(const bf16x8*)&Bt[rt * 64 + (((kk * 4 + q) ^ (rt & 7)) * 8)];
      }
#pragma unroll
      for (int m = 0; m < 4; ++m)
#pragma unroll
        for (int n = 0; n < 4; ++n)
          acc[m][n] = mfma16(ah[m], bh[n], acc[m][n]);
    }
  }

  float* Cg = out + (size_t)b * NQ_ * DIN_;
#pragma unroll
  for (int m = 0; m < 4; ++m)
#pragma unroll
    for (int n = 0; n < 4; ++n)
#pragma unroll
      for (int r = 0; r < 4; ++r) {
        const int row_g = brow + wr * 64 + m * 16 + q * 4 + r;
        const int col_g = bcol + wc * 64 + n * 16 + fr;
        Cg[(size_t)row_g * DIN_ + col_g] = acc[m][n][r];
      }
}

// ---------------------------------------------------------------------------
// x [B, NKV, DIN] fp32 -> xT [B, DIN, NKV] bf16
// ---------------------------------------------------------------------------
__global__ void transpose_x(const float* __restrict__ x, __bf16* __restrict__ xT)
{
  __shared__ float tile[32][33];
  const int b  = blockIdx.z;
  const int j0 = blockIdx.x * 32;   // NKV index
  const int i0 = blockIdx.y * 32;   // DIN index
  const float* xs = x  + (size_t)b * NKV_ * DIN_;
  __bf16*      xd = xT + (size_t)b * DIN_ * NKV_;
  const int tx = threadIdx.x, ty = threadIdx.y;  // 32 x 8
#pragma unroll
  for (int p = 0; p < 32; p += 8)
    tile[ty + p][tx] = xs[(size_t)(j0 + ty + p) * DIN_ + i0 + tx];
  __syncthreads();
#pragma unroll
  for (int p = 0; p < 32; p += 8)
    xd[(size_t)(i0 + ty + p) * NKV_ + j0 + tx] = (__bf16)tile[tx][ty + p];
}

// ---------------------------------------------------------------------------
// In-place row softmax over attn [rows x 2048]; also writes bf16 copy.
// ---------------------------------------------------------------------------
__global__ void softmax_rows(float* __restrict__ attn, __bf16* __restrict__ attnb)
{
  const int lane = threadIdx.x & 63;
  const int wv   = threadIdx.x >> 6;
  const size_t row = (size_t)blockIdx.x * 4 + wv;
  float*  p  = attn  + row * NKV_;
  __bf16* pb = attnb + row * NKV_;

  float4 v[8];
  float mx = -1e30f;
#pragma unroll
  for (int i = 0; i < 8; ++i) {
    v[i] = *(const float4*)&p[i * 256 + lane * 4];
    mx = fmaxf(mx, fmaxf(fmaxf(v[i].x, v[i].y), fmaxf(v[i].z, v[i].w)));
  }
#pragma unroll
  for (int off = 32; off; off >>= 1) mx = fmaxf(mx, __shfl_xor(mx, off, 64));

  float sum = 0.f;
#pragma unroll
  for (int i = 0; i < 8; ++i) {
    v[i].x = expf(v[i].x - mx);
    v[i].y = expf(v[i].y - mx);
    v[i].z = expf(v[i].z - mx);
    v[i].w = expf(v[i].w - mx);
    sum += v[i].x + v[i].y + v[i].z + v[i].w;
  }
#pragma unroll
  for (int off = 32; off; off >>= 1) sum += __shfl_xor(sum, off, 64);

  const float inv = 1.0f / sum;
#pragma unroll
  for (int i = 0; i < 8; ++i) {
    v[i].x *= inv; v[i].y *= inv; v[i].z *= inv; v[i].w *= inv;
    *(float4*)&p[i * 256 + lane * 4] = v[i];
    bf16x4 hv;
    hv[0] = (__bf16)v[i].x; hv[1] = (__bf16)v[i].y;
    hv[2] = (__bf16)v[i].z; hv[3] = (__bf16)v[i].w;
    *(bf16x4*)&pb[i * 256 + lane * 4] = hv;
  }
}

// ---------------------------------------------------------------------------
extern "C" void kernel_launch(void* const* d_in, const int* in_sizes, int n_in,
                              void* d_out, int out_size, void* d_ws, size_t ws_size,
                              hipStream_t stream)
{
  (void)in_sizes; (void)n_in; (void)out_size; (void)ws_size;
  const float* query  = (const float*)d_in[0];  // [8, 2048, 512]
  const float* key    = (const float*)d_in[1];  // [2048, 512]
  const float* x      = (const float*)d_in[2];  // [8, 2048, 512]
  const float* W_proj = (const float*)d_in[3];  // [512, 512]
  const float* b_proj = (const float*)d_in[4];  // [512]
  const float* W_px   = (const float*)d_in[5];  // [512, 512]
  const float* b_px   = (const float*)d_in[6];  // [512]

  float* out  = (float*)d_out;                          // [8, 2048, 512]
  float* attn = out + (size_t)B_ * NQ_ * DIN_;          // [8, 2048, 2048]

  const size_t PQE = (size_t)B_ * NQ_ * DQ_;            // 8.39M elements
  __bf16* qph = (__bf16*)d_ws;
  __bf16* qpl = qph + PQE;
  __bf16* kmh = qpl + PQE;
  __bf16* kml = kmh + PQE;
  __bf16* xT  = kml + PQE;                              // [8, 512, 2048] bf16
  // after score_gemm, qp/km are dead: reuse their 4*PQE bf16 region (=67.1MB)
  // for the bf16 attn copy (8*2048*2048 = 4*PQE elements exactly).
  __bf16* attnb = qph;

  // x^T (bf16) for the PV GEMM B-operand
  transpose_x<<<dim3(NKV_ / 32, DIN_ / 32, B_), dim3(32, 8), 0, stream>>>(x, xT);

  // q_proj = query @ W_proj^T + b_proj  -> split bf16
  proj_gemm<1><<<dim3(DQ_ / 128, (B_ * NQ_) / 128, 1), 256, 0, stream>>>(
      query, W_proj, qph, qpl, b_proj, nullptr);

  // k = x @ W_px^T + b_px + key        -> split bf16
  proj_gemm<2><<<dim3(DQ_ / 128, (B_ * NKV_) / 128, 1), 256, 0, stream>>>(
      x, W_px, kmh, kml, b_px, key);

  // raw scores into attn region of d_out (1D grid, XCD-swizzled)
  score_gemm<<<(NKV_ / 128) * (NQ_ / 128) * B_, 256, 0, stream>>>(
      qph, qpl, kmh, kml, attn);

  // softmax rows in place + bf16 copy into ws
  softmax_rows<<<(B_ * NQ_) / 4, 256, 0, stream>>>(attn, attnb);

  // out[b] = attn[b] @ x[b]  (1D grid, XCD-swizzled)
  pv_gemm<<<(DIN_ / 128) * (NQ_ / 128) * B_, 256, 0, stream>>>(attnb, xT, out);
}

// Round 4
// 292.763 us; speedup vs baseline: 1.2478x; 1.0334x over previous
//
#include <hip/hip_runtime.h>
#include <hip/hip_bf16.h>

// Problem constants
#define B_   8
#define NQ_  2048
#define NKV_ 2048
#define DQ_  512
#define DIN_ 512

using f32x4  = __attribute__((ext_vector_type(4))) float;
using bf16x4 = __attribute__((ext_vector_type(4))) __bf16;
using bf16x8 = __attribute__((ext_vector_type(8))) __bf16;

__device__ __forceinline__ f32x4 mfma16(bf16x8 a, bf16x8 b, f32x4 c) {
  return __builtin_amdgcn_mfma_f32_16x16x32_bf16(a, b, c, 0, 0, 0);
}

// async global->LDS, 16B per lane. LDS dest is wave-uniform base (+lane*16 in HW).
__device__ __forceinline__ void gload_lds16(const __bf16* g, __bf16* l) {
  __builtin_amdgcn_global_load_lds(
      (const __attribute__((address_space(1))) void*)g,
      (__attribute__((address_space(3))) void*)l, 16, 0, 0);
}

// bijective XCD-aware remap (nwg % 8 == 0)
__device__ __forceinline__ int xcd_swz(int bid, int nwg) {
  const int c = nwg >> 3;
  return (bid & 7) * c + (bid >> 3);
}

// ---------------------------------------------------------------------------
// Projection GEMM: C[m,n] = sum_k A[m,k]*B[n,k] + bias[n] (+ key), fp32 in,
// SPLIT bf16 hi/lo out. 3-product split accumulation (hh+hl+lh).
// ---------------------------------------------------------------------------
template<int EPI>
__global__ __launch_bounds__(256, 2)
void proj_gemm(const float* __restrict__ A, const float* __restrict__ Bm,
               __bf16* __restrict__ Ch, __bf16* __restrict__ Cl,
               const float* __restrict__ bias, const float* __restrict__ keyp)
{
  constexpr int PAD = 8;
  __shared__ __bf16 Ah[128][64 + PAD];
  __shared__ __bf16 Al[128][64 + PAD];
  __shared__ __bf16 Bh[128][64 + PAD];
  __shared__ __bf16 Bl[128][64 + PAD];

  const int tid  = threadIdx.x;
  const int lane = tid & 63;
  const int w    = tid >> 6;
  const int wr   = w >> 1;
  const int wc   = w & 1;
  const int brow = blockIdx.y * 128;
  const int bcol = blockIdx.x * 128;

  const float* Ag = A  + (size_t)brow * DQ_;
  const float* Bg = Bm + (size_t)bcol * DQ_;

  f32x4 acc[4][4] = {};

  const int sr = tid >> 4;
  const int sc = (tid & 15) * 4;

  for (int k0 = 0; k0 < DQ_; k0 += 64) {
    __syncthreads();
#pragma unroll
    for (int p = 0; p < 8; ++p) {
      const int r = p * 16 + sr;
      const float4 v = *(const float4*)(Ag + (size_t)r * DQ_ + k0 + sc);
      const float vv[4] = {v.x, v.y, v.z, v.w};
      bf16x4 h, l;
#pragma unroll
      for (int j = 0; j < 4; ++j) {
        const __bf16 hb = (__bf16)vv[j];
        h[j] = hb;
        l[j] = (__bf16)(vv[j] - (float)hb);
      }
      *(bf16x4*)&Ah[r][sc] = h;
      *(bf16x4*)&Al[r][sc] = l;
    }
#pragma unroll
    for (int p = 0; p < 8; ++p) {
      const int r = p * 16 + sr;
      const float4 v = *(const float4*)(Bg + (size_t)r * DQ_ + k0 + sc);
      const float vv[4] = {v.x, v.y, v.z, v.w};
      bf16x4 h, l;
#pragma unroll
      for (int j = 0; j < 4; ++j) {
        const __bf16 hb = (__bf16)vv[j];
        h[j] = hb;
        l[j] = (__bf16)(vv[j] - (float)hb);
      }
      *(bf16x4*)&Bh[r][sc] = h;
      *(bf16x4*)&Bl[r][sc] = l;
    }
    __syncthreads();
#pragma unroll
    for (int kk = 0; kk < 2; ++kk) {
      const int fr = lane & 15;
      const int fc = kk * 32 + (lane >> 4) * 8;
      bf16x8 ah[4], al[4], bh[4], bl[4];
#pragma unroll
      for (int m = 0; m < 4; ++m) {
        ah[m] = *(const bf16x8*)&Ah[wr * 64 + m * 16 + fr][fc];
        al[m] = *(const bf16x8*)&Al[wr * 64 + m * 16 + fr][fc];
      }
#pragma unroll
      for (int n = 0; n < 4; ++n) {
        bh[n] = *(const bf16x8*)&Bh[wc * 64 + n * 16 + fr][fc];
        bl[n] = *(const bf16x8*)&Bl[wc * 64 + n * 16 + fr][fc];
      }
#pragma unroll
      for (int m = 0; m < 4; ++m)
#pragma unroll
        for (int n = 0; n < 4; ++n) {
          acc[m][n] = mfma16(ah[m], bh[n], acc[m][n]);
          acc[m][n] = mfma16(ah[m], bl[n], acc[m][n]);
          acc[m][n] = mfma16(al[m], bh[n], acc[m][n]);
        }
    }
  }

#pragma unroll
  for (int m = 0; m < 4; ++m)
#pragma unroll
    for (int n = 0; n < 4; ++n)
#pragma unroll
      for (int r = 0; r < 4; ++r) {
        const int row_g = brow + wr * 64 + m * 16 + (lane >> 4) * 4 + r;
        const int col_g = bcol + wc * 64 + n * 16 + (lane & 15);
        float vv = acc[m][n][r] + bias[col_g];
        if (EPI == 2) vv += keyp[(size_t)(row_g & (NKV_ - 1)) * DQ_ + col_g];
        const __bf16 h = (__bf16)vv;
        Ch[(size_t)row_g * DQ_ + col_g] = h;
        Cl[(size_t)row_g * DQ_ + col_g] = (__bf16)(vv - (float)h);
      }
}

// ---------------------------------------------------------------------------
// Score GEMM, 256x256 tile, 512 threads (8 waves, 2M x 4N), phase-split
// schedule with double-buffered 128 KiB dynamic LDS.
// Real BK=32 per tile (LDS row = [hi 4 slots | lo 4 slots] of 8 bf16, XOR
// slot swizzle ^(row&7)). Per tile: 4 phases, each = quadrant (4m x 2n) x
// 3-product split = 24 MFMA, setprio-wrapped, raw s_barrier separated.
// Staging for tile t+1 issued in phases 0-1 of tile t into the idle buffer;
// drained by the tile-boundary __syncthreads (vmcnt0 ~3 phases after issue).
// ---------------------------------------------------------------------------
__global__ __launch_bounds__(512, 2)
void score_gemm(const __bf16* __restrict__ qph, const __bf16* __restrict__ qpl,
                const __bf16* __restrict__ kmh, const __bf16* __restrict__ kml,
                float* __restrict__ attn)
{
  extern __shared__ __bf16 lds[];      // A: 2*16384, B: 2*16384 (128 KiB)
  __bf16* At = lds;
  __bf16* Bt = lds + 32768;

  const int swz  = xcd_swz(blockIdx.x, gridDim.x);   // 512 blocks
  const int bx   = swz & 7;           // NKV block (256)
  const int by   = (swz >> 3) & 7;    // NQ block (256)
  const int b    = swz >> 6;          // batch

  const int t    = threadIdx.x;       // 0..511
  const int lane = t & 63;
  const int w    = t >> 6;            // 0..7
  const int wr   = w >> 2;            // 0..1 (M)
  const int wcn  = w & 3;             // 0..3 (N)
  const int brow = by * 256;
  const int bcol = bx * 256;

  // staging: thread t -> (srow = t>>3 in 0..63, physical slot = t&7)
  const int srow  = t >> 3;
  const int sslot = t & 7;
  const int sig   = sslot ^ (srow & 7);   // logical slot fetched by this thread
  const __bf16* aG = (sig < 4 ? qph : qpl) + ((size_t)b * NQ_  + brow + srow) * DQ_ + (sig & 3) * 8;
  const __bf16* bG = (sig < 4 ? kmh : kml) + ((size_t)b * NKV_ + bcol + srow) * DQ_ + (sig & 3) * 8;

  f32x4 acc[8][4] = {};
  const int fr = lane & 15;
  const int q  = lane >> 4;

  // prologue: stage tile 0 into buffer 0 (A: 4 issues of 64 rows, B: same)
#pragma unroll
  for (int j = 0; j < 4; ++j) gload_lds16(aG + (size_t)j * 64 * DQ_, At + j * 4096 + w * 512);
#pragma unroll
  for (int j = 0; j < 4; ++j) gload_lds16(bG + (size_t)j * 64 * DQ_, Bt + j * 4096 + w * 512);
  __syncthreads();

  const __bf16* aS = aG + 32;   // stage source for tile ts+1
  const __bf16* bS = bG + 32;

  for (int ts = 0; ts < 16; ++ts) {
    const int pb = ts & 1;
    const __bf16* Ab = At + pb * 16384;
    const __bf16* Bb = Bt + pb * 16384;
    __bf16* An = At + (pb ^ 1) * 16384;
    __bf16* Bn = Bt + (pb ^ 1) * 16384;

#pragma unroll
    for (int ph = 0; ph < 4; ++ph) {
      const int mh = ph >> 1;       // M half of wave tile
      const int nh = ph & 1;        // N half

      bf16x8 ah[4], al[4], bh[2], bl[2];
#pragma unroll
      for (int mi = 0; mi < 4; ++mi) {
        const int rA = wr * 128 + mh * 64 + mi * 16 + fr;
        ah[mi] = *(const bf16x8*)&Ab[rA * 64 + ((q       ^ (rA & 7)) * 8)];
        al[mi] = *(const bf16x8*)&Ab[rA * 64 + (((4 + q) ^ (rA & 7)) * 8)];
      }
#pragma unroll
      for (int ni = 0; ni < 2; ++ni) {
        const int rB = wcn * 64 + nh * 32 + ni * 16 + fr;
        bh[ni] = *(const bf16x8*)&Bb[rB * 64 + ((q       ^ (rB & 7)) * 8)];
        bl[ni] = *(const bf16x8*)&Bb[rB * 64 + (((4 + q) ^ (rB & 7)) * 8)];
      }

      if (ph == 0 && ts < 15) {
#pragma unroll
        for (int j = 0; j < 4; ++j) gload_lds16(aS + (size_t)j * 64 * DQ_, An + j * 4096 + w * 512);
      }
      if (ph == 1 && ts < 15) {
#pragma unroll
        for (int j = 0; j < 4; ++j) gload_lds16(bS + (size_t)j * 64 * DQ_, Bn + j * 4096 + w * 512);
      }

      __builtin_amdgcn_s_barrier();
      __builtin_amdgcn_s_setprio(1);
#pragma unroll
      for (int mi = 0; mi < 4; ++mi)
#pragma unroll
        for (int ni = 0; ni < 2; ++ni) {
          f32x4 c = acc[mh * 4 + mi][nh * 2 + ni];
          c = mfma16(ah[mi], bh[ni], c);
          c = mfma16(ah[mi], bl[ni], c);
          c = mfma16(al[mi], bh[ni], c);
          acc[mh * 4 + mi][nh * 2 + ni] = c;
        }
      __builtin_amdgcn_s_setprio(0);
      if (ph < 3) __builtin_amdgcn_s_barrier();
    }
    __syncthreads();                 // drains vmcnt: next tile staged & safe
    aS += 32; bS += 32;
  }

  float* Cg = attn + (size_t)b * NQ_ * NKV_;
#pragma unroll
  for (int m = 0; m < 8; ++m)
#pragma unroll
    for (int n = 0; n < 4; ++n)
#pragma unroll
      for (int r = 0; r < 4; ++r) {
        const int row_g = brow + wr * 128 + m * 16 + q * 4 + r;
        const int col_g = bcol + wcn * 64 + n * 16 + fr;
        Cg[(size_t)row_g * NKV_ + col_g] = acc[m][n][r];
      }
}

// ---------------------------------------------------------------------------
// PV GEMM: out[b,q,n] = sum_j attnb[b,q,j] * xT[b,n,j]. Both operands bf16,
// staged via global_load_lds with XOR swizzle. BK=64, 32 MFMA/step.
// ---------------------------------------------------------------------------
__global__ __launch_bounds__(256, 2)
void pv_gemm(const __bf16* __restrict__ attnb, const __bf16* __restrict__ xT,
             float* __restrict__ out)
{
  __shared__ __bf16 At[128 * 64];
  __shared__ __bf16 Bt[128 * 64];

  const int swz  = xcd_swz(blockIdx.x, gridDim.x);
  const int bx   = swz & 3;           // DIN block
  const int by   = (swz >> 2) & 15;   // NQ block
  const int b    = swz >> 6;          // batch

  const int t    = threadIdx.x;
  const int lane = t & 63;
  const int w    = t >> 6;
  const int wr   = w >> 1;
  const int wc   = w & 1;
  const int brow = by * 128;   // q rows
  const int bcol = bx * 128;   // din cols

  const int srow  = t >> 3;
  const int sslot = t & 7;
  const int sig   = sslot ^ (srow & 7);
  const __bf16* aG = attnb + ((size_t)b * NQ_ + brow + srow) * NKV_ + sig * 8;
  const __bf16* bG = xT + (size_t)b * DIN_ * NKV_ + (size_t)(bcol + srow) * NKV_ + sig * 8;
  __bf16* aL = At + w * 512;
  __bf16* bL = Bt + w * 512;

  f32x4 acc[4][4] = {};
  const int fr = lane & 15;
  const int q  = lane >> 4;

  for (int ks = 0; ks < NKV_ / 64; ++ks) {
    __syncthreads();
#pragma unroll
    for (int i = 0; i < 4; ++i) {
      gload_lds16(aG + (size_t)i * 32 * NKV_, aL + i * 2048);
      gload_lds16(bG + (size_t)i * 32 * NKV_, bL + i * 2048);
    }
    aG += 64; bG += 64;
    __syncthreads();

#pragma unroll
    for (int kk = 0; kk < 2; ++kk) {
      bf16x8 ah[4], bh[4];
#pragma unroll
      for (int m = 0; m < 4; ++m) {
        const int rt = wr * 64 + m * 16 + fr;
        ah[m] = *(const bf16x8*)&At[rt * 64 + (((kk * 4 + q) ^ (rt & 7)) * 8)];
      }
#pragma unroll
      for (int n = 0; n < 4; ++n) {
        const int rt = wc * 64 + n * 16 + fr;
        bh[n] = *(const bf16x8*)&Bt[rt * 64 + (((kk * 4 + q) ^ (rt & 7)) * 8)];
      }
#pragma unroll
      for (int m = 0; m < 4; ++m)
#pragma unroll
        for (int n = 0; n < 4; ++n)
          acc[m][n] = mfma16(ah[m], bh[n], acc[m][n]);
    }
  }

  float* Cg = out + (size_t)b * NQ_ * DIN_;
#pragma unroll
  for (int m = 0; m < 4; ++m)
#pragma unroll
    for (int n = 0; n < 4; ++n)
#pragma unroll
      for (int r = 0; r < 4; ++r) {
        const int row_g = brow + wr * 64 + m * 16 + q * 4 + r;
        const int col_g = bcol + wc * 64 + n * 16 + fr;
        Cg[(size_t)row_g * DIN_ + col_g] = acc[m][n][r];
      }
}

// ---------------------------------------------------------------------------
// x [B, NKV, DIN] fp32 -> xT [B, DIN, NKV] bf16
// ---------------------------------------------------------------------------
__global__ void transpose_x(const float* __restrict__ x, __bf16* __restrict__ xT)
{
  __shared__ float tile[32][33];
  const int b  = blockIdx.z;
  const int j0 = blockIdx.x * 32;   // NKV index
  const int i0 = blockIdx.y * 32;   // DIN index
  const float* xs = x  + (size_t)b * NKV_ * DIN_;
  __bf16*      xd = xT + (size_t)b * DIN_ * NKV_;
  const int tx = threadIdx.x, ty = threadIdx.y;  // 32 x 8
#pragma unroll
  for (int p = 0; p < 32; p += 8)
    tile[ty + p][tx] = xs[(size_t)(j0 + ty + p) * DIN_ + i0 + tx];
  __syncthreads();
#pragma unroll
  for (int p = 0; p < 32; p += 8)
    xd[(size_t)(i0 + ty + p) * NKV_ + j0 + tx] = (__bf16)tile[tx][ty + p];
}

// ---------------------------------------------------------------------------
// In-place row softmax over attn [rows x 2048]; also writes bf16 copy.
// ---------------------------------------------------------------------------
__global__ void softmax_rows(float* __restrict__ attn, __bf16* __restrict__ attnb)
{
  const int lane = threadIdx.x & 63;
  const int wv   = threadIdx.x >> 6;
  const size_t row = (size_t)blockIdx.x * 4 + wv;
  float*  p  = attn  + row * NKV_;
  __bf16* pb = attnb + row * NKV_;

  float4 v[8];
  float mx = -1e30f;
#pragma unroll
  for (int i = 0; i < 8; ++i) {
    v[i] = *(const float4*)&p[i * 256 + lane * 4];
    mx = fmaxf(mx, fmaxf(fmaxf(v[i].x, v[i].y), fmaxf(v[i].z, v[i].w)));
  }
#pragma unroll
  for (int off = 32; off; off >>= 1) mx = fmaxf(mx, __shfl_xor(mx, off, 64));

  float sum = 0.f;
#pragma unroll
  for (int i = 0; i < 8; ++i) {
    v[i].x = expf(v[i].x - mx);
    v[i].y = expf(v[i].y - mx);
    v[i].z = expf(v[i].z - mx);
    v[i].w = expf(v[i].w - mx);
    sum += v[i].x + v[i].y + v[i].z + v[i].w;
  }
#pragma unroll
  for (int off = 32; off; off >>= 1) sum += __shfl_xor(sum, off, 64);

  const float inv = 1.0f / sum;
#pragma unroll
  for (int i = 0; i < 8; ++i) {
    v[i].x *= inv; v[i].y *= inv; v[i].z *= inv; v[i].w *= inv;
    *(float4*)&p[i * 256 + lane * 4] = v[i];
    bf16x4 hv;
    hv[0] = (__bf16)v[i].x; hv[1] = (__bf16)v[i].y;
    hv[2] = (__bf16)v[i].z; hv[3] = (__bf16)v[i].w;
    *(bf16x4*)&pb[i * 256 + lane * 4] = hv;
  }
}

// ---------------------------------------------------------------------------
extern "C" void kernel_launch(void* const* d_in, const int* in_sizes, int n_in,
                              void* d_out, int out_size, void* d_ws, size_t ws_size,
                              hipStream_t stream)
{
  (void)in_sizes; (void)n_in; (void)out_size; (void)ws_size;
  const float* query  = (const float*)d_in[0];  // [8, 2048, 512]
  const float* key    = (const float*)d_in[1];  // [2048, 512]
  const float* x      = (const float*)d_in[2];  // [8, 2048, 512]
  const float* W_proj = (const float*)d_in[3];  // [512, 512]
  const float* b_proj = (const float*)d_in[4];  // [512]
  const float* W_px   = (const float*)d_in[5];  // [512, 512]
  const float* b_px   = (const float*)d_in[6];  // [512]

  float* out  = (float*)d_out;                          // [8, 2048, 512]
  float* attn = out + (size_t)B_ * NQ_ * DIN_;          // [8, 2048, 2048]

  const size_t PQE = (size_t)B_ * NQ_ * DQ_;            // 8.39M elements
  __bf16* qph = (__bf16*)d_ws;
  __bf16* qpl = qph + PQE;
  __bf16* kmh = qpl + PQE;
  __bf16* kml = kmh + PQE;
  __bf16* xT  = kml + PQE;                              // [8, 512, 2048] bf16
  // after score_gemm, qp/km are dead: reuse their 4*PQE bf16 region (=67.1MB)
  // for the bf16 attn copy (8*2048*2048 = 4*PQE elements exactly).
  __bf16* attnb = qph;

  // allow 128 KiB dynamic LDS for score_gemm (idempotent, capture-safe)
  hipFuncSetAttribute((const void*)score_gemm,
                      hipFuncAttributeMaxDynamicSharedMemorySize, 131072);

  // x^T (bf16) for the PV GEMM B-operand
  transpose_x<<<dim3(NKV_ / 32, DIN_ / 32, B_), dim3(32, 8), 0, stream>>>(x, xT);

  // q_proj = query @ W_proj^T + b_proj  -> split bf16
  proj_gemm<1><<<dim3(DQ_ / 128, (B_ * NQ_) / 128, 1), 256, 0, stream>>>(
      query, W_proj, qph, qpl, b_proj, nullptr);

  // k = x @ W_px^T + b_px + key        -> split bf16
  proj_gemm<2><<<dim3(DQ_ / 128, (B_ * NKV_) / 128, 1), 256, 0, stream>>>(
      x, W_px, kmh, kml, b_px, key);

  // raw scores into attn region of d_out (256^2 tiles, XCD-swizzled)
  score_gemm<<<(NKV_ / 256) * (NQ_ / 256) * B_, 512, 131072, stream>>>(
      qph, qpl, kmh, kml, attn);

  // softmax rows in place + bf16 copy into ws
  softmax_rows<<<(B_ * NQ_) / 4, 256, 0, stream>>>(attn, attnb);

  // out[b] = attn[b] @ x[b]  (1D grid, XCD-swizzled)
  pv_gemm<<<(DIN_ / 128) * (NQ_ / 128) * B_, 256, 0, stream>>>(attnb, xT, out);
}